// Round 4
// baseline (176.265 us; speedup 1.0000x reference)
//
#include <hip/hip_runtime.h>
#include <stdint.h>

#define N_BATCH 32
#define B_OBJ   36
#define D_DIM   2048
#define Q_DIM   1024

typedef __bf16 bf16x8 __attribute__((ext_vector_type(8)));
typedef float  f32x4  __attribute__((ext_vector_type(4)));

__device__ __forceinline__ uint16_t f2bf(float f) {
    uint32_t u = __builtin_bit_cast(uint32_t, f);
    uint32_t r = (u + 0x7FFFu + ((u >> 16) & 1u)) >> 16;   // RNE
    return (uint16_t)r;
}

__device__ __forceinline__ void gld_lds16(const void* g, void* l) {
    __builtin_amdgcn_global_load_lds(
        (const __attribute__((address_space(1))) uint32_t*)g,
        (__attribute__((address_space(3))) uint32_t*)l, 16, 0, 0);
}

// ---- transpose + fp32->bf16, 64x64 tiles, vectorized ----
__global__ __launch_bounds__(256) void transpose_all(
    const float* __restrict__ W1, const float* __restrict__ W2,
    const float* __restrict__ W3,
    uint16_t* __restrict__ W1t, uint16_t* __restrict__ W2t,
    uint16_t* __restrict__ W3t) {
    __shared__ float tile[64][65];
    int gy = blockIdx.y;
    const float* W; uint16_t* Wt; int K, k0;
    if (gy < 32)      { W = W1; Wt = W1t; K = 2048; k0 = gy * 64; }
    else if (gy < 64) { W = W2; Wt = W2t; K = 2048; k0 = (gy - 32) * 64; }
    else              { W = W3; Wt = W3t; K = 1024; k0 = (gy - 64) * 64; }
    int n0 = blockIdx.x * 64;
    int t = threadIdx.x;
    {
        int r = t >> 4, c = (t & 15) * 4;
#pragma unroll
        for (int p = 0; p < 4; ++p)
            *(float4*)&tile[r + p * 16][c] =
                *(const float4*)&W[(size_t)(k0 + r + p * 16) * 2048 + n0 + c];
    }
    __syncthreads();
    {
        int n = t >> 2, kb = (t & 3) * 16;
#pragma unroll
        for (int g4 = 0; g4 < 4; ++g4) {
            int k = kb + g4 * 4;
            ushort4 o;
            o.x = f2bf(tile[k][n]);     o.y = f2bf(tile[k + 1][n]);
            o.z = f2bf(tile[k + 2][n]); o.w = f2bf(tile[k + 3][n]);
            *(ushort4*)&Wt[(size_t)(n0 + n) * K + k0 + k] = o;
        }
    }
}

// ---- qe GEMM: qpart[z] = q @ W3 over K-chunk z (M=32, N=2048, split-K=4) ----
__global__ __launch_bounds__(256) void qk_gemm(
    const float* __restrict__ q,
    const uint16_t* __restrict__ W3t,
    float* __restrict__ qpart) {
    __shared__ __align__(16) uint16_t As[32][32];
    __shared__ __align__(16) uint16_t Bs[128][32];
    int t = threadIdx.x, lane = t & 63, wave = t >> 6;
    int l15 = lane & 15, quad = lane >> 4;
    int n0 = blockIdx.x * 128;
    int kbase = blockIdx.y * 256;
    f32x4 acc[2][2] = {};
    int ar = t >> 3, ac = (t & 7) * 4;
    int br = t >> 2, bk = (t & 3) * 8;

    for (int k0 = 0; k0 < 256; k0 += 32) {
        __syncthreads();
        float4 av = *(const float4*)&q[(size_t)ar * Q_DIM + kbase + k0 + ac];
        ushort4 a4;
        a4.x = f2bf(av.x); a4.y = f2bf(av.y); a4.z = f2bf(av.z); a4.w = f2bf(av.w);
        *(ushort4*)&As[ar][ac] = a4;
        *(uint4*)&Bs[br][bk]      = *(const uint4*)&W3t[(size_t)(n0 + br) * Q_DIM + kbase + k0 + bk];
        *(uint4*)&Bs[br + 64][bk] = *(const uint4*)&W3t[(size_t)(n0 + br + 64) * Q_DIM + kbase + k0 + bk];
        __syncthreads();
        bf16x8 af[2], bfr[2];
        af[0]  = *(const bf16x8*)&As[l15][quad * 8];
        af[1]  = *(const bf16x8*)&As[16 + l15][quad * 8];
        bfr[0] = *(const bf16x8*)&Bs[wave * 32 + l15][quad * 8];
        bfr[1] = *(const bf16x8*)&Bs[wave * 32 + 16 + l15][quad * 8];
#pragma unroll
        for (int i = 0; i < 2; ++i)
#pragma unroll
            for (int j = 0; j < 2; ++j)
                acc[i][j] = __builtin_amdgcn_mfma_f32_16x16x32_bf16(af[i], bfr[j], acc[i][j], 0, 0, 0);
    }
    float* dst = qpart + (size_t)blockIdx.y * 32 * D_DIM;
#pragma unroll
    for (int i = 0; i < 2; ++i)
#pragma unroll
        for (int j = 0; j < 2; ++j) {
            int n = n0 + wave * 32 + j * 16 + l15;
#pragma unroll
            for (int r = 0; r < 4; ++r)
                dst[(size_t)(i * 16 + quad * 4 + r) * D_DIM + n] = acc[i][j][r];
        }
}

// ---- fused: qe = relu(sum_z qpart + b3) (in regs); u[n,i,d] = bf16(v*qe) ----
// grid (4, N_BATCH), 128 threads; block owns a 512-float d-chunk of batch nb.
__global__ __launch_bounds__(128) void qe_make_u(
    const float* __restrict__ qpart, const float* __restrict__ b3,
    const float* __restrict__ v, uint16_t* __restrict__ u) {
    int nb = blockIdx.y;
    int d4 = blockIdx.x * 128 + threadIdx.x;          // float4 index in row (512/row)
    const float4* p = (const float4*)qpart;
    size_t base = (size_t)nb * 512 + d4;
    float4 s0 = p[base], s1 = p[16384 + base], s2 = p[32768 + base], s3 = p[49152 + base];
    float4 b = ((const float4*)b3)[d4];
    float4 qe;
    qe.x = fmaxf(s0.x + s1.x + s2.x + s3.x + b.x, 0.f);
    qe.y = fmaxf(s0.y + s1.y + s2.y + s3.y + b.y, 0.f);
    qe.z = fmaxf(s0.z + s1.z + s2.z + s3.z + b.z, 0.f);
    qe.w = fmaxf(s0.w + s1.w + s2.w + s3.w + b.w, 0.f);
    const float4* v4 = (const float4*)v;
    ushort4* u4 = (ushort4*)u;
    size_t rb = (size_t)nb * B_OBJ * 512 + d4;
#pragma unroll 4
    for (int i = 0; i < B_OBJ; ++i) {
        float4 vv = v4[rb + (size_t)i * 512];
        ushort4 o;
        o.x = f2bf(vv.x * qe.x);
        o.y = f2bf(vv.y * qe.y);
        o.z = f2bf(vv.z * qe.z);
        o.w = f2bf(vv.w * qe.w);
        u4[rb + (size_t)i * 512] = o;
    }
}

// ---- per-batch GEMM: tile M=48(36 real) x N=128, K=2048, BK=64 ----
// Depth-3 counted-vmcnt pipeline: 3 LDS buffers; stage k+3 is issued right
// after the read-barrier of step k, so each stage has ~2 full K-steps of
// flight time. Per-wave loads/step L = {6,6,5,5} (22 regions of 1KB); each
// wave waits on ITS OWN counter: vmcnt(2L) steady, L/0 at tail. No vmcnt(0)
// drain in the main loop. LDS = 3 x 22528 B = 67584 B (dynamic).
// mode 0: pairsum epilogue -> x (bf16). mode 1: relu(+bias) -> out (f32).
__global__ __launch_bounds__(256) void gemm_batch(
    const uint16_t* __restrict__ A,    // 1152 x 2048 bf16
    const uint16_t* __restrict__ Bt,   // 2048 x 2048 bf16 (n-major)
    const float* __restrict__ bias,
    void* __restrict__ Cv,
    int mode) {
    // Buffer: As = 48x64 bf16 (3072 u16), Bs = 128x64 bf16 (8192 u16)
    // -> 11264 u16 = 22528 B; x3 buffers. Epilogue reuses as yt[48][132] f32.
    extern __shared__ __align__(16) uint16_t smem[];
    float* yt = (float*)smem;

    int t = threadIdx.x, lane = t & 63, wave = t >> 6;
    int l15 = lane & 15, quad = lane >> 4;
    int nb = blockIdx.y;
    int n0 = blockIdx.x * 128;
    const uint16_t* Ab = A + (size_t)nb * B_OBJ * D_DIM;

    // 22 regions of 1KB, r = wave + 4c: 0..5 = A (h=r/3,g=r%3), 6..21 = B.
    // Region = 16 rows x 32 u16; lane -> row lane>>2, swizzled 16B slot.
    const uint16_t* gp[6];
    int loff[6];
    int wslot = (lane & 3) ^ ((lane >> 2) & 3);
#pragma unroll
    for (int c = 0; c < 6; ++c) {
        int r = wave + 4 * c;
        int rr = (r < 22) ? r : 0;
        if (rr < 6) {
            int h = rr / 3, g = rr % 3;
            int row = g * 16 + (lane >> 2), kk = h * 32 + wslot * 8;
            gp[c] = Ab + (size_t)row * D_DIM + kk;   // rows 36..47: junk (pads into qpart)
            loff[c] = h * 1536 + g * 512;
        } else {
            int rb = rr - 6, h = rb >> 3, g = rb & 7;
            int row = g * 16 + (lane >> 2), kk = h * 32 + wslot * 8;
            gp[c] = Bt + (size_t)(n0 + row) * D_DIM + kk;
            loff[c] = 3072 + h * 4096 + g * 512;
        }
    }

    f32x4 acc[3][2] = {};
    // read-side swizzled slot: all rows this lane reads have row&3 == l15&3
    int rslot = quad ^ (l15 & 3);
    bool w01 = (wave < 2);   // waves 0,1 issue 6 loads/step; waves 2,3 issue 5

#define STAGE(kk, bi)                                                    \
    {                                                                    \
        _Pragma("unroll")                                                \
        for (int c = 0; c < 6; ++c)                                      \
            if (wave + 4 * c < 22)                                       \
                gld_lds16(gp[c] + (kk), smem + (bi) * 11264 + loff[c]);  \
    }

    // prologue: fill all 3 buffers; wait for stage0 only (2 stages in flight)
    STAGE(0, 0);
    STAGE(64, 1);
    STAGE(128, 2);
    if (w01) asm volatile("s_waitcnt vmcnt(12)" ::: "memory");
    else     asm volatile("s_waitcnt vmcnt(10)" ::: "memory");
    __builtin_amdgcn_s_barrier();

    int cur = 0;
    for (int k = 0; k < 32; ++k) {
        const uint16_t* As = smem + cur * 11264;
        const uint16_t* Bs = As + 3072;
#pragma unroll
        for (int s = 0; s < 2; ++s) {
            bf16x8 af[3], bfr[2];
#pragma unroll
            for (int i = 0; i < 3; ++i)
                af[i] = *(const bf16x8*)(As + s * 1536 + (i * 16 + l15) * 32 + rslot * 8);
#pragma unroll
            for (int j = 0; j < 2; ++j)
                bfr[j] = *(const bf16x8*)(Bs + s * 4096 + (wave * 32 + j * 16 + l15) * 32 + rslot * 8);
#pragma unroll
            for (int i = 0; i < 3; ++i)
#pragma unroll
                for (int j = 0; j < 2; ++j)
                    acc[i][j] = __builtin_amdgcn_mfma_f32_16x16x32_bf16(af[i], bfr[j], acc[i][j], 0, 0, 0);
        }
        if (k == 31) break;
        __builtin_amdgcn_s_barrier();              // all waves done reading buf[cur]
        if (k <= 28) {
            STAGE((k + 3) * 64, cur);              // refill freed buffer
            // wait: stage k+1 retired; stages k+2,k+3 (2L loads) stay in flight
            if (w01) asm volatile("s_waitcnt vmcnt(12)" ::: "memory");
            else     asm volatile("s_waitcnt vmcnt(10)" ::: "memory");
        } else if (k == 29) {
            if (w01) asm volatile("s_waitcnt vmcnt(6)" ::: "memory");
            else     asm volatile("s_waitcnt vmcnt(5)" ::: "memory");
        } else {   // k == 30: drain everything (also frees smem for epilogue)
            asm volatile("s_waitcnt vmcnt(0)" ::: "memory");
        }
        __builtin_amdgcn_s_barrier();              // next buffer ready
        cur = (cur == 2) ? 0 : cur + 1;
    }
#undef STAGE

    if (mode == 0) {
        uint16_t* X = (uint16_t*)Cv;
        __syncthreads();   // all waves done with K-loop before smem reuse as yt
#pragma unroll
        for (int i = 0; i < 3; ++i)
#pragma unroll
            for (int j = 0; j < 2; ++j)
#pragma unroll
                for (int r = 0; r < 4; ++r)
                    yt[(i * 16 + quad * 4 + r) * 132 + wave * 32 + j * 16 + l15] = acc[i][j][r];
        __syncthreads();
        int col = t & 127, half = t >> 7;
        float b = bias[n0 + col];
        float z[36];
#pragma unroll
        for (int j = 0; j < 36; ++j) z[j] = yt[j * 132 + col];
#pragma unroll
        for (int ii = 0; ii < 18; ++ii) {
            int i = half * 18 + ii;
            float zi = z[i] + b;
            float s = 0.f;
#pragma unroll
            for (int j = 0; j < 36; ++j) s += fmaxf(zi + z[j], 0.f);
            X[(size_t)(nb * B_OBJ + i) * D_DIM + n0 + col] = f2bf(s);
        }
    } else {
        float* O = (float*)Cv;
#pragma unroll
        for (int i = 0; i < 3; ++i)
#pragma unroll
            for (int r = 0; r < 4; ++r) {
                int row = i * 16 + quad * 4 + r;
                if (row < B_OBJ) {
#pragma unroll
                    for (int j = 0; j < 2; ++j) {
                        int cc = n0 + wave * 32 + j * 16 + l15;
                        O[(size_t)(nb * B_OBJ + row) * D_DIM + cc] =
                            fmaxf(acc[i][j][r] + bias[cc], 0.f);
                    }
                }
            }
    }
}

extern "C" void kernel_launch(void* const* d_in, const int* in_sizes, int n_in,
                              void* d_out, int out_size, void* d_ws, size_t ws_size,
                              hipStream_t stream) {
    const float* v  = (const float*)d_in[0];
    const float* q  = (const float*)d_in[1];
    const float* W1 = (const float*)d_in[2];
    const float* b1 = (const float*)d_in[3];
    const float* W2 = (const float*)d_in[4];
    const float* b2 = (const float*)d_in[5];
    const float* W3 = (const float*)d_in[6];
    const float* b3 = (const float*)d_in[7];
    float* out = (float*)d_out;

    char* ws = (char*)d_ws;
    uint16_t* W1t   = (uint16_t*)(ws + 0);           // 8 MiB
    uint16_t* W2t   = (uint16_t*)(ws + 8388608);     // 8 MiB
    uint16_t* W3t   = (uint16_t*)(ws + 16777216);    // 4 MiB, dead after qk_gemm
    uint16_t* u     = (uint16_t*)(ws + 16777216);    // 4.5 MiB (overlays dead W3t)
    float*    qpart = (float*)   (ws + 21495808);    // 1 MiB (also pads u over-reads)
    uint16_t* x     = (uint16_t*)(ws + 22806528);    // 4.5 MiB (ends 27525120)

    // allow 67584 B of dynamic LDS for the depth-3 pipeline (host-side, capture-safe)
    static bool attr_done = false;
    if (!attr_done) {
        (void)hipFuncSetAttribute((const void*)gemm_batch,
                                  hipFuncAttributeMaxDynamicSharedMemorySize, 67584);
        attr_done = true;
    }

    transpose_all<<<dim3(32, 80), 256, 0, stream>>>(W1, W2, W3, W1t, W2t, W3t);

    qk_gemm<<<dim3(16, 4), 256, 0, stream>>>(q, W3t, qpart);

    qe_make_u<<<dim3(4, N_BATCH), 128, 0, stream>>>(qpart, b3, v, u);

    // GEMM1 + fused pairsum -> x (bf16)
    gemm_batch<<<dim3(16, N_BATCH), 256, 67584, stream>>>(u, W1t, b1, x, 0);

    // GEMM2 + bias + relu -> out (f32)
    gemm_batch<<<dim3(16, N_BATCH), 256, 67584, stream>>>(x, W2t, b2, out, 1);
}

// Round 6
// 171.910 us; speedup vs baseline: 1.0253x; 1.0253x over previous
//
#include <hip/hip_runtime.h>
#include <stdint.h>

#define N_BATCH 32
#define B_OBJ   36
#define D_DIM   2048
#define Q_DIM   1024

typedef __bf16 bf16x8 __attribute__((ext_vector_type(8)));
typedef float  f32x4  __attribute__((ext_vector_type(4)));

__device__ __forceinline__ uint16_t f2bf(float f) {
    uint32_t u = __builtin_bit_cast(uint32_t, f);
    uint32_t r = (u + 0x7FFFu + ((u >> 16) & 1u)) >> 16;   // RNE
    return (uint16_t)r;
}

__device__ __forceinline__ void gld_lds16(const void* g, void* l) {
    __builtin_amdgcn_global_load_lds(
        (const __attribute__((address_space(1))) uint32_t*)g,
        (__attribute__((address_space(3))) uint32_t*)l, 16, 0, 0);
}

// ---- transpose + fp32->bf16, 64x64 tiles, vectorized ----
__global__ __launch_bounds__(256) void transpose_all(
    const float* __restrict__ W1, const float* __restrict__ W2,
    const float* __restrict__ W3,
    uint16_t* __restrict__ W1t, uint16_t* __restrict__ W2t,
    uint16_t* __restrict__ W3t) {
    __shared__ float tile[64][65];
    int gy = blockIdx.y;
    const float* W; uint16_t* Wt; int K, k0;
    if (gy < 32)      { W = W1; Wt = W1t; K = 2048; k0 = gy * 64; }
    else if (gy < 64) { W = W2; Wt = W2t; K = 2048; k0 = (gy - 32) * 64; }
    else              { W = W3; Wt = W3t; K = 1024; k0 = (gy - 64) * 64; }
    int n0 = blockIdx.x * 64;
    int t = threadIdx.x;
    {
        int r = t >> 4, c = (t & 15) * 4;
#pragma unroll
        for (int p = 0; p < 4; ++p)
            *(float4*)&tile[r + p * 16][c] =
                *(const float4*)&W[(size_t)(k0 + r + p * 16) * 2048 + n0 + c];
    }
    __syncthreads();
    {
        int n = t >> 2, kb = (t & 3) * 16;
#pragma unroll
        for (int g4 = 0; g4 < 4; ++g4) {
            int k = kb + g4 * 4;
            ushort4 o;
            o.x = f2bf(tile[k][n]);     o.y = f2bf(tile[k + 1][n]);
            o.z = f2bf(tile[k + 2][n]); o.w = f2bf(tile[k + 3][n]);
            *(ushort4*)&Wt[(size_t)(n0 + n) * K + k0 + k] = o;
        }
    }
}

// ---- qe GEMM: qpart[z] = q @ W3 over K-chunk z (M=32, N=2048, split-K=4) ----
__global__ __launch_bounds__(256) void qk_gemm(
    const float* __restrict__ q,
    const uint16_t* __restrict__ W3t,
    float* __restrict__ qpart) {
    __shared__ __align__(16) uint16_t As[32][32];
    __shared__ __align__(16) uint16_t Bs[128][32];
    int t = threadIdx.x, lane = t & 63, wave = t >> 6;
    int l15 = lane & 15, quad = lane >> 4;
    int n0 = blockIdx.x * 128;
    int kbase = blockIdx.y * 256;
    f32x4 acc[2][2] = {};
    int ar = t >> 3, ac = (t & 7) * 4;
    int br = t >> 2, bk = (t & 3) * 8;

    for (int k0 = 0; k0 < 256; k0 += 32) {
        __syncthreads();
        float4 av = *(const float4*)&q[(size_t)ar * Q_DIM + kbase + k0 + ac];
        ushort4 a4;
        a4.x = f2bf(av.x); a4.y = f2bf(av.y); a4.z = f2bf(av.z); a4.w = f2bf(av.w);
        *(ushort4*)&As[ar][ac] = a4;
        *(uint4*)&Bs[br][bk]      = *(const uint4*)&W3t[(size_t)(n0 + br) * Q_DIM + kbase + k0 + bk];
        *(uint4*)&Bs[br + 64][bk] = *(const uint4*)&W3t[(size_t)(n0 + br + 64) * Q_DIM + kbase + k0 + bk];
        __syncthreads();
        bf16x8 af[2], bfr[2];
        af[0]  = *(const bf16x8*)&As[l15][quad * 8];
        af[1]  = *(const bf16x8*)&As[16 + l15][quad * 8];
        bfr[0] = *(const bf16x8*)&Bs[wave * 32 + l15][quad * 8];
        bfr[1] = *(const bf16x8*)&Bs[wave * 32 + 16 + l15][quad * 8];
#pragma unroll
        for (int i = 0; i < 2; ++i)
#pragma unroll
            for (int j = 0; j < 2; ++j)
                acc[i][j] = __builtin_amdgcn_mfma_f32_16x16x32_bf16(af[i], bfr[j], acc[i][j], 0, 0, 0);
    }
    float* dst = qpart + (size_t)blockIdx.y * 32 * D_DIM;
#pragma unroll
    for (int i = 0; i < 2; ++i)
#pragma unroll
        for (int j = 0; j < 2; ++j) {
            int n = n0 + wave * 32 + j * 16 + l15;
#pragma unroll
            for (int r = 0; r < 4; ++r)
                dst[(size_t)(i * 16 + quad * 4 + r) * D_DIM + n] = acc[i][j][r];
        }
}

// ---- fused: qe = relu(sum_z qpart + b3) (in regs); u[n,i,d] = bf16(v*qe) ----
// grid (4, N_BATCH), 128 threads; block owns a 512-float d-chunk of batch nb.
__global__ __launch_bounds__(128) void qe_make_u(
    const float* __restrict__ qpart, const float* __restrict__ b3,
    const float* __restrict__ v, uint16_t* __restrict__ u) {
    int nb = blockIdx.y;
    int d4 = blockIdx.x * 128 + threadIdx.x;          // float4 index in row (512/row)
    const float4* p = (const float4*)qpart;
    size_t base = (size_t)nb * 512 + d4;
    float4 s0 = p[base], s1 = p[16384 + base], s2 = p[32768 + base], s3 = p[49152 + base];
    float4 b = ((const float4*)b3)[d4];
    float4 qe;
    qe.x = fmaxf(s0.x + s1.x + s2.x + s3.x + b.x, 0.f);
    qe.y = fmaxf(s0.y + s1.y + s2.y + s3.y + b.y, 0.f);
    qe.z = fmaxf(s0.z + s1.z + s2.z + s3.z + b.z, 0.f);
    qe.w = fmaxf(s0.w + s1.w + s2.w + s3.w + b.w, 0.f);
    const float4* v4 = (const float4*)v;
    ushort4* u4 = (ushort4*)u;
    size_t rb = (size_t)nb * B_OBJ * 512 + d4;
#pragma unroll 4
    for (int i = 0; i < B_OBJ; ++i) {
        float4 vv = v4[rb + (size_t)i * 512];
        ushort4 o;
        o.x = f2bf(vv.x * qe.x);
        o.y = f2bf(vv.y * qe.y);
        o.z = f2bf(vv.z * qe.z);
        o.w = f2bf(vv.w * qe.w);
        u4[rb + (size_t)i * 512] = o;
    }
}

// ---- pair-batched GEMM: tile M=96 (2 batches x 48) x N=128, K=2048, BK=64 ----
// W is shared across batches, so stacking 2 batches per block halves B
// re-staging (the round-4 L2-BW wall: 45 KB/CU/step -> 28 KB/CU/step).
// 512 threads = 8 waves tiled 2(M) x 4(N); each wave: M48 x N32, acc 3x2.
// Depth-2 counted-vmcnt pipeline, T2 slot swizzle on stage-source + read.
// 28 staging regions of 1KB/step; waves 0-3 issue 4, waves 4-7 issue 3.
// mode 0: pairsum epilogue -> x (bf16). mode 1: relu(+bias) -> out (f32).
__global__ __launch_bounds__(512) void gemm_batch(
    const uint16_t* __restrict__ A,    // 1152 x 2048 bf16 (32 batches x 36 rows)
    const uint16_t* __restrict__ Bt,   // 2048 x 2048 bf16 (n-major)
    const float* __restrict__ bias,
    void* __restrict__ Cv,
    int mode) {
    // Buffer: As = [2 halves][96 rows][32 u16] = 6144 u16 (12 KB),
    //         Bs = [2][128][32] = 8192 u16 (16 KB) -> 14336 u16 = 28672 B; x2.
    // Epilogue reuses buffer as yt[96][132] f32 = 50688 B (< 57344).
    __shared__ __align__(16) uint16_t smem[2][14336];
    float* yt = (float*)&smem[0][0];

    int t = threadIdx.x, lane = t & 63, wave = t >> 6;
    int l15 = lane & 15, quad = lane >> 4;
    int wr = wave >> 2, wc = wave & 3;         // wave tile: rows wr*48, cols wc*32
    int nbp = blockIdx.y;                      // batch pair: batches 2*nbp, 2*nbp+1
    int n0 = blockIdx.x * 128;
    const uint16_t* Ab = A + (size_t)nbp * 72 * D_DIM;   // 72 real rows per pair

    // 28 regions of 1KB, region r = wave + 8c (waves 0-3: c<4, waves 4-7: c<3):
    //  r<12:  A: g=r>>1 (row group g*16 of 96), h=r&1 (K-half).
    //         LDS rows 0-47 = batch0 (36 real + 12 junk), 48-95 = batch1
    //         (real arow = ldsrow-12; junk 84-95 reads next pair / qpart pad).
    //  r>=12: B: rb=r-12, g=rb>>1 (row group of 128), h=rb&1.
    // Region = 16 rows x 32 u16; lane -> row lane>>2, swizzled 16B slot.
    const uint16_t* gp[4];
    int loff[4];
    int wslot = (lane & 3) ^ ((lane >> 2) & 3);
#pragma unroll
    for (int c = 0; c < 4; ++c) {
        int r = wave + 8 * c;
        int rr = (r < 28) ? r : 0;
        if (rr < 12) {
            int g = rr >> 1, h = rr & 1;
            int arow = g * 16 + (lane >> 2) - (g >= 3 ? 12 : 0);
            gp[c] = Ab + (size_t)arow * D_DIM + h * 32 + wslot * 8;
            loff[c] = h * 3072 + g * 512;
        } else {
            int rb = rr - 12, g = rb >> 1, h = rb & 1;
            int brow = g * 16 + (lane >> 2);
            gp[c] = Bt + (size_t)(n0 + brow) * D_DIM + h * 32 + wslot * 8;
            loff[c] = 6144 + h * 4096 + g * 512;
        }
    }

    f32x4 acc[3][2] = {};
    // read-side swizzled slot: all rows this lane reads have row&3 == l15&3
    int rslot = quad ^ (l15 & 3);

#define STAGE(kk, bi)                                    \
    {                                                    \
        _Pragma("unroll")                                \
        for (int c = 0; c < 4; ++c)                      \
            if (wave + 8 * c < 28)                       \
                gld_lds16(gp[c] + (kk), &smem[bi][loff[c]]); \
    }
#define WAIT_L()                                                      \
    {                                                                 \
        if (wave < 4) asm volatile("s_waitcnt vmcnt(4)" ::: "memory");\
        else          asm volatile("s_waitcnt vmcnt(3)" ::: "memory");\
    }

    // prologue: fill both buffers; wait for stage0 only (stage1 in flight)
    STAGE(0, 0);
    STAGE(64, 1);
    WAIT_L();
    __builtin_amdgcn_s_barrier();

    for (int k = 0; k < 32; ++k) {
        int cur = k & 1;
        const uint16_t* As = &smem[cur][0];
        const uint16_t* Bs = As + 6144;
#pragma unroll
        for (int s = 0; s < 2; ++s) {
            bf16x8 af[3], bfr[2];
#pragma unroll
            for (int i = 0; i < 3; ++i)
                af[i] = *(const bf16x8*)(As + s * 3072 + (wr * 48 + i * 16 + l15) * 32 + rslot * 8);
#pragma unroll
            for (int j = 0; j < 2; ++j)
                bfr[j] = *(const bf16x8*)(Bs + s * 4096 + (wc * 32 + j * 16 + l15) * 32 + rslot * 8);
#pragma unroll
            for (int i = 0; i < 3; ++i)
#pragma unroll
                for (int j = 0; j < 2; ++j)
                    acc[i][j] = __builtin_amdgcn_mfma_f32_16x16x32_bf16(af[i], bfr[j], acc[i][j], 0, 0, 0);
        }
        if (k == 31) break;
        __builtin_amdgcn_s_barrier();              // all waves done reading buf[cur]
        if (k < 30) {
            STAGE((k + 2) * 64, cur);              // refill freed buffer
            WAIT_L();                              // stage k+1 retired; k+2 in flight
        } else {                                   // k == 30: drain stage(31)
            asm volatile("s_waitcnt vmcnt(0)" ::: "memory");
        }
        __builtin_amdgcn_s_barrier();              // next buffer ready
    }
#undef STAGE
#undef WAIT_L

    if (mode == 0) {
        uint16_t* X = (uint16_t*)Cv;
        __syncthreads();   // all waves done with K-loop before smem reuse as yt
#pragma unroll
        for (int i = 0; i < 3; ++i)
#pragma unroll
            for (int j = 0; j < 2; ++j)
#pragma unroll
                for (int r = 0; r < 4; ++r)
                    yt[(wr * 48 + i * 16 + quad * 4 + r) * 132 + wc * 32 + j * 16 + l15] = acc[i][j][r];
        __syncthreads();
        int col = t & 127, sub = t >> 7;           // sub: 0..3
        int b = sub >> 1, half = sub & 1;          // batch-in-pair, row-half
        float bv = bias[n0 + col];
        float z[36];
#pragma unroll
        for (int j = 0; j < 36; ++j) z[j] = yt[(b * 48 + j) * 132 + col];
#pragma unroll
        for (int ii = 0; ii < 18; ++ii) {
            int i = half * 18 + ii;
            float zi = z[i] + bv;
            float s = 0.f;
#pragma unroll
            for (int j = 0; j < 36; ++j) s += fmaxf(zi + z[j], 0.f);
            X[(size_t)((nbp * 2 + b) * B_OBJ + i) * D_DIM + n0 + col] = f2bf(s);
        }
    } else {
        float* O = (float*)Cv;
#pragma unroll
        for (int i = 0; i < 3; ++i)
#pragma unroll
            for (int r = 0; r < 4; ++r) {
                int obj = i * 16 + quad * 4 + r;   // row within this wave's batch
                if (obj < B_OBJ) {
#pragma unroll
                    for (int j = 0; j < 2; ++j) {
                        int cc = n0 + wc * 32 + j * 16 + l15;
                        O[(size_t)((nbp * 2 + wr) * B_OBJ + obj) * D_DIM + cc] =
                            fmaxf(acc[i][j][r] + bias[cc], 0.f);
                    }
                }
            }
    }
}

extern "C" void kernel_launch(void* const* d_in, const int* in_sizes, int n_in,
                              void* d_out, int out_size, void* d_ws, size_t ws_size,
                              hipStream_t stream) {
    const float* v  = (const float*)d_in[0];
    const float* q  = (const float*)d_in[1];
    const float* W1 = (const float*)d_in[2];
    const float* b1 = (const float*)d_in[3];
    const float* W2 = (const float*)d_in[4];
    const float* b2 = (const float*)d_in[5];
    const float* W3 = (const float*)d_in[6];
    const float* b3 = (const float*)d_in[7];
    float* out = (float*)d_out;

    char* ws = (char*)d_ws;
    uint16_t* W1t   = (uint16_t*)(ws + 0);           // 8 MiB
    uint16_t* W2t   = (uint16_t*)(ws + 8388608);     // 8 MiB
    uint16_t* W3t   = (uint16_t*)(ws + 16777216);    // 4 MiB, dead after qk_gemm
    uint16_t* u     = (uint16_t*)(ws + 16777216);    // 4.5 MiB (overlays dead W3t)
    float*    qpart = (float*)   (ws + 21495808);    // 1 MiB (also pads u over-reads)
    uint16_t* x     = (uint16_t*)(ws + 22806528);    // 4.5 MiB (ends 27525120; ws pads over-reads)

    transpose_all<<<dim3(32, 80), 256, 0, stream>>>(W1, W2, W3, W1t, W2t, W3t);

    qk_gemm<<<dim3(16, 4), 256, 0, stream>>>(q, W3t, qpart);

    qe_make_u<<<dim3(4, N_BATCH), 128, 0, stream>>>(qpart, b3, v, u);

    // GEMM1 + fused pairsum -> x (bf16); 16 batch pairs
    gemm_batch<<<dim3(16, 16), 512, 0, stream>>>(u, W1t, b1, x, 0);

    // GEMM2 + bias + relu -> out (f32)
    gemm_batch<<<dim3(16, 16), 512, 0, stream>>>(x, W2t, b2, out, 1);
}